// Round 4
// baseline (1105.682 us; speedup 1.0000x reference)
//
#include <hip/hip_runtime.h>
#include <hip/hip_bf16.h>
#include <cstddef>

#define TT 512
#define BB 8
#define HH 1024
#define MM 32
#define NVOCAB 32000
#define NROWS (TT * BB)   // 4096

typedef __attribute__((ext_vector_type(8))) short bf16x8;
typedef __attribute__((ext_vector_type(4))) float f32x4;

__device__ __forceinline__ void gload_lds16(const void* g, void* l) {
    __builtin_amdgcn_global_load_lds(
        (const __attribute__((address_space(1))) void*)g,
        (__attribute__((address_space(3))) void*)l, 16, 0, 0);
}

__device__ __forceinline__ unsigned short bf16_bits(float f) {
    __hip_bfloat16 h = __float2bfloat16(f);
    return *reinterpret_cast<unsigned short*>(&h);
}

// ---------------------------------------------------------------------------
// 1) hidden[r][h] = emb[x[r]][h] + pos_emb[t][h],  r = t*8+b
// ---------------------------------------------------------------------------
__global__ __launch_bounds__(256) void k_embed(const int* __restrict__ x,
                                               const float* __restrict__ emb,
                                               const float* __restrict__ pos,
                                               float* __restrict__ out) {
    int r = blockIdx.x;
    int t = r >> 3;
    int idx = x[r];
    const float4* e = (const float4*)(emb + (size_t)idx * HH);
    const float4* p = (const float4*)(pos + (size_t)t * HH);
    float4* o = (float4*)(out + (size_t)r * HH);
    int i = threadIdx.x;
    float4 ev = e[i], pv = p[i];
    o[i] = make_float4(ev.x + pv.x, ev.y + pv.y, ev.z + pv.z, ev.w + pv.w);
}

// ---------------------------------------------------------------------------
// 2) q/k proj + tau-softmax
// ---------------------------------------------------------------------------
__global__ __launch_bounds__(256) void k_proj_softmax(const float* __restrict__ hid,
                                                      const float* __restrict__ Wq,
                                                      const float* __restrict__ Wk,
                                                      float* __restrict__ aout,
                                                      float* __restrict__ bout_) {
    __shared__ float xs[HH];
    __shared__ float qk[64];
    int r = blockIdx.x;
    int tid = threadIdx.x;
    ((float4*)xs)[tid] = ((const float4*)(hid + (size_t)r * HH))[tid];
    __syncthreads();

    int col = tid >> 2;
    int seg = tid & 3;
    const float* W = (col < 32) ? Wq : Wk;
    int c = col & 31;
    float s = 0.f;
    int h0 = seg * 256;
    #pragma unroll 8
    for (int hh = 0; hh < 256; ++hh)
        s = fmaf(xs[h0 + hh], W[(size_t)(h0 + hh) * MM + c], s);
    s += __shfl_down(s, 1);
    s += __shfl_down(s, 2);
    if (seg == 0) qk[col] = s;
    __syncthreads();

    if (tid < 64) {
        float v = qk[tid] * 0.5f;
        float m = v;
        #pragma unroll
        for (int o = 16; o >= 1; o >>= 1) m = fmaxf(m, __shfl_xor(m, o));
        float e = expf(v - m);
        float ssum = e;
        #pragma unroll
        for (int o = 16; o >= 1; o >>= 1) ssum += __shfl_xor(ssum, o);
        float res = e / ssum;
        if (tid < 32) aout[(size_t)r * MM + tid] = res;
        else          bout_[(size_t)r * MM + (tid - 32)] = res;
    }
}

// ---------------------------------------------------------------------------
// 3) leaky associative scan -> bf16 spikes.
//    (b,i,j) cells independent given a/b streams: 128 blocks (8 b x 16 ig),
//    64 threads = 2 i-rows x 32 j. a/b staged in LDS per 128-t chunk.
// ---------------------------------------------------------------------------
#define CHUNK 128
__global__ __launch_bounds__(64) void k_scan(const float* __restrict__ a,
                                             const float* __restrict__ bsm,
                                             __hip_bfloat16* __restrict__ spk) {
    __shared__ float sa[CHUNK * 2];
    __shared__ float sb[CHUNK * MM];
    int bb = blockIdx.x >> 4;        // batch 0..7
    int ig = blockIdx.x & 15;        // i-group 0..15
    int tid = threadIdx.x;           // 0..63
    int i2 = tid >> 5, j = tid & 31;
    int i = ig * 2 + i2;
    float mem = 0.f;
    for (int t0 = 0; t0 < TT; t0 += CHUNK) {
        __syncthreads();
        // stage b rows: CHUNK*32 floats = 1024 float4
        for (int v = tid; v < CHUNK * 8; v += 64) {
            int tt = v >> 3, p = v & 7;
            ((float4*)sb)[v] = ((const float4*)bsm)[((size_t)(t0 + tt) * BB + bb) * 8 + p];
        }
        // stage a pair: CHUNK*2 floats
        for (int v = tid; v < CHUNK * 2; v += 64) {
            int tt = v >> 1, ii = v & 1;
            sa[v] = a[((size_t)(t0 + tt) * BB + bb) * MM + ig * 2 + ii];
        }
        __syncthreads();
        for (int tt = 0; tt < CHUNK; ++tt) {
            float av = sa[tt * 2 + i2];
            float bv = sb[tt * MM + j];
            mem = fmaf(0.9f, mem, av * bv);
            float sv = (mem > 1.0f) ? 1.0f : 0.0f;
            spk[((size_t)(t0 + tt) * BB + bb) * HH + i * MM + j] = __float2bfloat16(sv);
            mem -= sv;
        }
    }
}

// ---------------------------------------------------------------------------
// 4a) W [K][N] fp32 -> Wt [N][K] bf16  (tiled transpose + convert)
// ---------------------------------------------------------------------------
__global__ __launch_bounds__(256) void k_transpose_cvt(const float* __restrict__ W,
                                                       __hip_bfloat16* __restrict__ Wt,
                                                       int K, int N) {
    __shared__ float t[32][33];
    int n0 = blockIdx.x * 32;
    int k0 = blockIdx.y * 32;
    int tx = threadIdx.x & 31, ty = threadIdx.x >> 5;   // ty 0..7
    #pragma unroll
    for (int r = 0; r < 4; ++r)
        t[ty + r * 8][tx] = W[(size_t)(k0 + ty + r * 8) * N + n0 + tx];
    __syncthreads();
    #pragma unroll
    for (int r = 0; r < 4; ++r)
        Wt[(size_t)(n0 + ty + r * 8) * K + k0 + tx] = __float2bfloat16(t[tx][ty + r * 8]);
}

// ---------------------------------------------------------------------------
// 4b) fp32 -> bf16 elementwise (4/thread)
// ---------------------------------------------------------------------------
__global__ __launch_bounds__(256) void k_f2b(const float* __restrict__ X,
                                             __hip_bfloat16* __restrict__ Y) {
    int i = blockIdx.x * 256 + threadIdx.x;
    float4 v = ((const float4*)X)[i];
    ushort4 o;
    o.x = bf16_bits(v.x);
    o.y = bf16_bits(v.y);
    o.z = bf16_bits(v.z);
    o.w = bf16_bits(v.w);
    ((ushort4*)Y)[i] = o;
}

// ---------------------------------------------------------------------------
// 5) bf16 MFMA GEMM, m97 structure: 128x128 tile, 4 waves (2x2), BK=32.
//    Grid: (x = M/128 row index, y = N/128 col index) -> linear dispatch id is
//    row-fastest; bijective XCD chunk swizzle (nwg % 8 == 0) gives each XCD
//    contiguous column panels -> B-panel L2 reuse.
//    A [M][K] bf16 row-major, Bt [N][K] bf16 row-major.
//    C fp32 [M][N] = (relu?)(A @ Bt^T + bias)
// ---------------------------------------------------------------------------
template <int DO_RELU>
__global__ __launch_bounds__(256) void k_gemm_bf16(const __hip_bfloat16* __restrict__ A,
                                                   const __hip_bfloat16* __restrict__ Bt,
                                                   const float* __restrict__ bias,
                                                   float* __restrict__ C,
                                                   int N, int K) {
    __shared__ __align__(16) __hip_bfloat16 As[128 * 32];
    __shared__ __align__(16) __hip_bfloat16 Bs[128 * 32];
    int tid = threadIdx.x;
    int lane = tid & 63;
    int w = tid >> 6;
    int wr = w >> 1, wc = w & 1;

    // ---- bijective XCD chunk swizzle, row-fastest tile order ----
    int gx = gridDim.x;                       // = 32 (M/128)
    int nwg = gx * gridDim.y;
    int lin = blockIdx.x + blockIdx.y * gx;   // dispatch order
    int q = nwg >> 3;                         // nwg % 8 == 0 for all our grids
    int swz = (lin & 7) * q + (lin >> 3);
    int row = swz & 31;                       // gx == 32 always here
    int col = swz >> 5;
    int brow = row * 128;
    int bcol = col * 128;

    f32x4 acc[4][4] = {};

    const __hip_bfloat16* gA = A  + (size_t)(brow + (tid >> 2)) * K + (tid & 3) * 8;
    const __hip_bfloat16* gB = Bt + (size_t)(bcol + (tid >> 2)) * K + (tid & 3) * 8;
    __hip_bfloat16* lA0 = As + (size_t)(w * 512);
    __hip_bfloat16* lB0 = Bs + (size_t)(w * 512);
    const size_t rstep = (size_t)64 * K;

    int r0 = wr * 64 + (lane & 15);
    int c0 = wc * 64 + (lane & 15);
    int kb = lane >> 4;

    for (int k0 = 0; k0 < K; k0 += 32) {
        gload_lds16(gA + k0,         lA0);
        gload_lds16(gA + k0 + rstep, lA0 + 2048);
        gload_lds16(gB + k0,         lB0);
        gload_lds16(gB + k0 + rstep, lB0 + 2048);
        __syncthreads();

        bf16x8 af[4], bfr[4];
        #pragma unroll
        for (int m = 0; m < 4; ++m)
            af[m] = ((const bf16x8*)As)[(r0 + m * 16) * 4 + kb];
        #pragma unroll
        for (int n = 0; n < 4; ++n)
            bfr[n] = ((const bf16x8*)Bs)[(c0 + n * 16) * 4 + kb];
        #pragma unroll
        for (int m = 0; m < 4; ++m)
            #pragma unroll
            for (int n = 0; n < 4; ++n)
                acc[m][n] = __builtin_amdgcn_mfma_f32_16x16x32_bf16(af[m], bfr[n], acc[m][n], 0, 0, 0);
        __syncthreads();
    }

    int ccol = bcol + wc * 64 + (lane & 15);
    int crow = brow + wr * 64 + ((lane >> 4) << 2);
    #pragma unroll
    for (int n = 0; n < 4; ++n) {
        float bv = bias[ccol + n * 16];
        #pragma unroll
        for (int m = 0; m < 4; ++m) {
            #pragma unroll
            for (int q2 = 0; q2 < 4; ++q2) {
                float v = acc[m][n][q2] + bv;
                if (DO_RELU) v = fmaxf(v, 0.f);
                C[(size_t)(crow + m * 16 + q2) * N + ccol + n * 16] = v;
            }
        }
    }
}

// ---------------------------------------------------------------------------
// 6) in-place row LayerNorm
// ---------------------------------------------------------------------------
__global__ __launch_bounds__(256) void k_layernorm(float* __restrict__ X,
                                                   const float* __restrict__ g,
                                                   const float* __restrict__ bta) {
    __shared__ float rs[4], rss[4];
    int r = blockIdx.x;
    int tid = threadIdx.x;
    float* row = X + (size_t)r * HH;
    float4 v = ((float4*)row)[tid];
    float s = v.x + v.y + v.z + v.w;
    float ss = v.x * v.x + v.y * v.y + v.z * v.z + v.w * v.w;
    #pragma unroll
    for (int o = 32; o >= 1; o >>= 1) {
        s += __shfl_down(s, o);
        ss += __shfl_down(ss, o);
    }
    int w = tid >> 6;
    if ((tid & 63) == 0) { rs[w] = s; rss[w] = ss; }
    __syncthreads();
    float S = rs[0] + rs[1] + rs[2] + rs[3];
    float SS = rss[0] + rss[1] + rss[2] + rss[3];
    float mu = S * (1.f / HH);
    float var = SS * (1.f / HH) - mu * mu;
    float inv = rsqrtf(var + 1e-5f);
    float4 gg = ((const float4*)g)[tid];
    float4 bb = ((const float4*)bta)[tid];
    float4 o;
    o.x = (v.x - mu) * inv * gg.x + bb.x;
    o.y = (v.y - mu) * inv * gg.y + bb.y;
    o.z = (v.z - mu) * inv * gg.z + bb.z;
    o.w = (v.w - mu) * inv * gg.w + bb.w;
    ((float4*)row)[tid] = o;
}

// ---------------------------------------------------------------------------
extern "C" void kernel_launch(void* const* d_in, const int* in_sizes, int n_in,
                              void* d_out, int out_size, void* d_ws, size_t ws_size,
                              hipStream_t stream) {
    const int*   x    = (const int*)d_in[0];
    const float* emb  = (const float*)d_in[1];
    const float* pos  = (const float*)d_in[2];
    const float* Wq1  = (const float*)d_in[3];
    const float* Wk1  = (const float*)d_in[4];
    const float* Wq2  = (const float*)d_in[5];
    const float* Wk2  = (const float*)d_in[6];
    const float* Wq3  = (const float*)d_in[7];
    const float* Wk3  = (const float*)d_in[8];
    const float* W2   = (const float*)d_in[9];
    const float* b2   = (const float*)d_in[10];
    const float* W3   = (const float*)d_in[11];
    const float* b3   = (const float*)d_in[12];
    const float* W4   = (const float*)d_in[13];
    const float* b4   = (const float*)d_in[14];
    const float* Wout = (const float*)d_in[15];
    const float* bout = (const float*)d_in[16];
    const float* ln2g = (const float*)d_in[17];
    const float* ln2b = (const float*)d_in[18];
    const float* ln3g = (const float*)d_in[19];
    const float* ln3b = (const float*)d_in[20];

    char* wsp = (char*)d_ws;
    float* h   = (float*)wsp;                 wsp += (size_t)NROWS * HH * 4;   // 16 MB
    float* pa  = (float*)wsp;                 wsp += (size_t)NROWS * MM * 4;
    float* pb  = (float*)wsp;                 wsp += (size_t)NROWS * MM * 4;
    __hip_bfloat16* spkb = (__hip_bfloat16*)wsp; wsp += (size_t)NROWS * HH * 2;  // 8 MB
    __hip_bfloat16* hb   = (__hip_bfloat16*)wsp; wsp += (size_t)NROWS * HH * 2;  // 8 MB
    __hip_bfloat16* W2t  = (__hip_bfloat16*)wsp; wsp += (size_t)HH * HH * 2;     // 2 MB
    __hip_bfloat16* W3t  = (__hip_bfloat16*)wsp; wsp += (size_t)HH * HH * 2;
    __hip_bfloat16* W4t  = (__hip_bfloat16*)wsp; wsp += (size_t)HH * HH * 2;
    __hip_bfloat16* Wot  = (__hip_bfloat16*)wsp; wsp += (size_t)NVOCAB * HH * 2; // 64 MB
    float* out = (float*)d_out;

    // weight prep (bf16, transposed to [N][K])
    k_transpose_cvt<<<dim3(HH / 32, HH / 32), 256, 0, stream>>>(W2, W2t, HH, HH);
    k_transpose_cvt<<<dim3(HH / 32, HH / 32), 256, 0, stream>>>(W3, W3t, HH, HH);
    k_transpose_cvt<<<dim3(HH / 32, HH / 32), 256, 0, stream>>>(W4, W4t, HH, HH);
    k_transpose_cvt<<<dim3(NVOCAB / 32, HH / 32), 256, 0, stream>>>(Wout, Wot, HH, NVOCAB);

    dim3 gmid(NROWS / 128, HH / 128);         // (rows=32, cols=8)
    dim3 gout(NROWS / 128, NVOCAB / 128);     // (rows=32, cols=250)

    k_embed<<<NROWS, 256, 0, stream>>>(x, emb, pos, h);

    // layer 1
    k_proj_softmax<<<NROWS, 256, 0, stream>>>(h, Wq1, Wk1, pa, pb);
    k_scan<<<128, 64, 0, stream>>>(pa, pb, spkb);
    k_gemm_bf16<1><<<gmid, 256, 0, stream>>>(spkb, W2t, b2, h, HH, HH);
    k_layernorm<<<NROWS, 256, 0, stream>>>(h, ln2g, ln2b);

    // layer 2
    k_proj_softmax<<<NROWS, 256, 0, stream>>>(h, Wq2, Wk2, pa, pb);
    k_scan<<<128, 64, 0, stream>>>(pa, pb, spkb);
    k_gemm_bf16<1><<<gmid, 256, 0, stream>>>(spkb, W3t, b3, h, HH, HH);
    k_layernorm<<<NROWS, 256, 0, stream>>>(h, ln3g, ln3b);

    // layer 3
    k_proj_softmax<<<NROWS, 256, 0, stream>>>(h, Wq3, Wk3, pa, pb);
    k_scan<<<128, 64, 0, stream>>>(pa, pb, spkb);
    k_gemm_bf16<1><<<gmid, 256, 0, stream>>>(spkb, W4t, b4, h, HH, HH);

    // output projection
    k_f2b<<<NROWS * HH / 1024, 256, 0, stream>>>(h, hb);
    k_gemm_bf16<0><<<gout, 256, 0, stream>>>(hb, Wot, bout, out, NVOCAB, HH);
}

// Round 5
// 739.226 us; speedup vs baseline: 1.4957x; 1.4957x over previous
//
#include <hip/hip_runtime.h>
#include <hip/hip_bf16.h>
#include <cstddef>

#define TT 512
#define BB 8
#define HH 1024
#define MM 32
#define NVOCAB 32000
#define NROWS (TT * BB)   // 4096

typedef __attribute__((ext_vector_type(8))) short bf16x8;
typedef __attribute__((ext_vector_type(4))) float f32x4;

__device__ __forceinline__ void gload_lds16(const void* g, void* l) {
    __builtin_amdgcn_global_load_lds(
        (const __attribute__((address_space(1))) void*)g,
        (__attribute__((address_space(3))) void*)l, 16, 0, 0);
}

// ---------------------------------------------------------------------------
// 1) fused (embed?) + q/k proj + tau-softmax. 8 rows per block.
//    FUSE=1: row = emb[x[r]] + pos[t] computed into LDS (h never materialized)
//    FUSE=0: row read from hid.
// ---------------------------------------------------------------------------
template <int FUSE>
__global__ __launch_bounds__(256) void k_proj(const int* __restrict__ xw,
                                              const float* __restrict__ emb,
                                              const float* __restrict__ pos,
                                              const float* __restrict__ hid,
                                              const float* __restrict__ Wq,
                                              const float* __restrict__ Wk,
                                              float* __restrict__ aout,
                                              float* __restrict__ bout_) {
    __shared__ float xs[8][HH];      // 32 KB
    __shared__ float qks[8][64];
    int r0r = blockIdx.x * 8;
    int tid = threadIdx.x;

    #pragma unroll
    for (int rr = 0; rr < 8; ++rr) {
        int r = r0r + rr;
        float4 v;
        if (FUSE) {
            int idx = xw[r];
            float4 ev = ((const float4*)(emb + (size_t)idx * HH))[tid];
            float4 pv = ((const float4*)(pos + (size_t)(r >> 3) * HH))[tid];
            v = make_float4(ev.x + pv.x, ev.y + pv.y, ev.z + pv.z, ev.w + pv.w);
        } else {
            v = ((const float4*)(hid + (size_t)r * HH))[tid];
        }
        ((float4*)xs[rr])[tid] = v;
    }
    __syncthreads();

    int col = tid >> 2;       // 0..63 (0..31 q, 32..63 k)
    int seg = tid & 3;
    const float* W = (col < 32) ? Wq : Wk;
    int c = col & 31;
    int h0 = seg * 256;
    float s[8] = {0.f, 0.f, 0.f, 0.f, 0.f, 0.f, 0.f, 0.f};
    for (int hh = 0; hh < 256; ++hh) {
        float wv = W[(size_t)(h0 + hh) * MM + c];
        #pragma unroll
        for (int rr = 0; rr < 8; ++rr)
            s[rr] = fmaf(xs[rr][h0 + hh], wv, s[rr]);
    }
    #pragma unroll
    for (int rr = 0; rr < 8; ++rr) {
        float t = s[rr];
        t += __shfl_down(t, 1);
        t += __shfl_down(t, 2);
        if (seg == 0) qks[rr][col] = t;
    }
    __syncthreads();

    // softmax: each wave handles one row; lanes 0..31 = q cols, 32..63 = k cols
    #pragma unroll
    for (int g = 0; g < 2; ++g) {
        int rr = g * 4 + (tid >> 6);
        int lane = tid & 63;
        float v = qks[rr][lane] * 0.5f;      // / tau
        float m = v;
        #pragma unroll
        for (int o = 16; o >= 1; o >>= 1) m = fmaxf(m, __shfl_xor(m, o));
        float e = expf(v - m);
        float ss = e;
        #pragma unroll
        for (int o = 16; o >= 1; o >>= 1) ss += __shfl_xor(ss, o);
        float res = e / ss;
        size_t r = r0r + rr;
        if (lane < 32) aout[r * MM + lane] = res;
        else           bout_[r * MM + (lane - 32)] = res;
    }
}

// ---------------------------------------------------------------------------
// 2) leaky associative scan -> bf16 spikes. 128 blocks (8 b x 16 ig), 64 thr.
// ---------------------------------------------------------------------------
#define CHUNK 128
__global__ __launch_bounds__(64) void k_scan(const float* __restrict__ a,
                                             const float* __restrict__ bsm,
                                             __hip_bfloat16* __restrict__ spk) {
    __shared__ float sa[CHUNK * 2];
    __shared__ float sb[CHUNK * MM];
    int bb = blockIdx.x >> 4;
    int ig = blockIdx.x & 15;
    int tid = threadIdx.x;
    int i2 = tid >> 5, j = tid & 31;
    int i = ig * 2 + i2;
    float mem = 0.f;
    for (int t0 = 0; t0 < TT; t0 += CHUNK) {
        __syncthreads();
        for (int v = tid; v < CHUNK * 8; v += 64) {
            int tt = v >> 3, p = v & 7;
            ((float4*)sb)[v] = ((const float4*)bsm)[((size_t)(t0 + tt) * BB + bb) * 8 + p];
        }
        for (int v = tid; v < CHUNK * 2; v += 64) {
            int tt = v >> 1, ii = v & 1;
            sa[v] = a[((size_t)(t0 + tt) * BB + bb) * MM + ig * 2 + ii];
        }
        __syncthreads();
        for (int tt = 0; tt < CHUNK; ++tt) {
            float av = sa[tt * 2 + i2];
            float bv = sb[tt * MM + j];
            mem = fmaf(0.9f, mem, av * bv);
            float sv = (mem > 1.0f) ? 1.0f : 0.0f;
            spk[((size_t)(t0 + tt) * BB + bb) * HH + i * MM + j] = __float2bfloat16(sv);
            mem -= sv;
        }
    }
}

// ---------------------------------------------------------------------------
// 3a) W [1024][1024] fp32 -> Wt [1024][1024] bf16 transposed; 3 weights fused
// ---------------------------------------------------------------------------
__global__ __launch_bounds__(256) void k_transpose_cvt3(const float* __restrict__ Wa,
                                                        const float* __restrict__ Wb,
                                                        const float* __restrict__ Wc,
                                                        __hip_bfloat16* __restrict__ Ta,
                                                        __hip_bfloat16* __restrict__ Tb,
                                                        __hip_bfloat16* __restrict__ Tc) {
    const float* W = (blockIdx.z == 0) ? Wa : (blockIdx.z == 1) ? Wb : Wc;
    __hip_bfloat16* Wt = (blockIdx.z == 0) ? Ta : (blockIdx.z == 1) ? Tb : Tc;
    __shared__ float t[32][33];
    int n0 = blockIdx.x * 32;
    int k0 = blockIdx.y * 32;
    int tx = threadIdx.x & 31, ty = threadIdx.x >> 5;
    #pragma unroll
    for (int r = 0; r < 4; ++r)
        t[ty + r * 8][tx] = W[(size_t)(k0 + ty + r * 8) * HH + n0 + tx];
    __syncthreads();
    #pragma unroll
    for (int r = 0; r < 4; ++r)
        Wt[(size_t)(n0 + ty + r * 8) * HH + k0 + tx] = __float2bfloat16(t[tx][ty + r * 8]);
}

// ---------------------------------------------------------------------------
// 3b) W [K][N] fp32 -> Wt [N][K] bf16 (Wout)
// ---------------------------------------------------------------------------
__global__ __launch_bounds__(256) void k_transpose_cvt(const float* __restrict__ W,
                                                       __hip_bfloat16* __restrict__ Wt,
                                                       int K, int N) {
    __shared__ float t[32][33];
    int n0 = blockIdx.x * 32;
    int k0 = blockIdx.y * 32;
    int tx = threadIdx.x & 31, ty = threadIdx.x >> 5;
    #pragma unroll
    for (int r = 0; r < 4; ++r)
        t[ty + r * 8][tx] = W[(size_t)(k0 + ty + r * 8) * N + n0 + tx];
    __syncthreads();
    #pragma unroll
    for (int r = 0; r < 4; ++r)
        Wt[(size_t)(n0 + ty + r * 8) * K + k0 + tx] = __float2bfloat16(t[tx][ty + r * 8]);
}

// ---------------------------------------------------------------------------
// 4) bf16 MFMA GEMM (mid layers), m97 128x128, 4 waves, BK=32, R3 ordering.
//    BF16_OUT=1 writes bf16 (layer 3 -> hb), else fp32.
// ---------------------------------------------------------------------------
template <int DO_RELU, int BF16_OUT>
__global__ __launch_bounds__(256) void k_gemm_bf16(const __hip_bfloat16* __restrict__ A,
                                                   const __hip_bfloat16* __restrict__ Bt,
                                                   const float* __restrict__ bias,
                                                   void* __restrict__ Cv,
                                                   int N, int K) {
    __shared__ __align__(16) __hip_bfloat16 As[128 * 32];
    __shared__ __align__(16) __hip_bfloat16 Bs[128 * 32];
    int tid = threadIdx.x;
    int lane = tid & 63;
    int w = tid >> 6;
    int wr = w >> 1, wc = w & 1;
    int brow = blockIdx.y * 128;
    int bcol = blockIdx.x * 128;

    f32x4 acc[4][4] = {};

    const __hip_bfloat16* gA = A  + (size_t)(brow + (tid >> 2)) * K + (tid & 3) * 8;
    const __hip_bfloat16* gB = Bt + (size_t)(bcol + (tid >> 2)) * K + (tid & 3) * 8;
    __hip_bfloat16* lA0 = As + (size_t)(w * 512);
    __hip_bfloat16* lB0 = Bs + (size_t)(w * 512);
    const size_t rstep = (size_t)64 * K;

    int r0 = wr * 64 + (lane & 15);
    int c0 = wc * 64 + (lane & 15);
    int kb = lane >> 4;

    for (int k0 = 0; k0 < K; k0 += 32) {
        gload_lds16(gA + k0,         lA0);
        gload_lds16(gA + k0 + rstep, lA0 + 2048);
        gload_lds16(gB + k0,         lB0);
        gload_lds16(gB + k0 + rstep, lB0 + 2048);
        __syncthreads();

        bf16x8 af[4], bfr[4];
        #pragma unroll
        for (int m = 0; m < 4; ++m)
            af[m] = ((const bf16x8*)As)[(r0 + m * 16) * 4 + kb];
        #pragma unroll
        for (int n = 0; n < 4; ++n)
            bfr[n] = ((const bf16x8*)Bs)[(c0 + n * 16) * 4 + kb];
        #pragma unroll
        for (int m = 0; m < 4; ++m)
            #pragma unroll
            for (int n = 0; n < 4; ++n)
                acc[m][n] = __builtin_amdgcn_mfma_f32_16x16x32_bf16(af[m], bfr[n], acc[m][n], 0, 0, 0);
        __syncthreads();
    }

    int ccol = bcol + wc * 64 + (lane & 15);
    int crow = brow + wr * 64 + ((lane >> 4) << 2);
    #pragma unroll
    for (int n = 0; n < 4; ++n) {
        float bv = bias[ccol + n * 16];
        #pragma unroll
        for (int m = 0; m < 4; ++m) {
            #pragma unroll
            for (int q2 = 0; q2 < 4; ++q2) {
                float v = acc[m][n][q2] + bv;
                if (DO_RELU) v = fmaxf(v, 0.f);
                size_t off = (size_t)(crow + m * 16 + q2) * N + ccol + n * 16;
                if (BF16_OUT) ((__hip_bfloat16*)Cv)[off] = __float2bfloat16(v);
                else          ((float*)Cv)[off] = v;
            }
        }
    }
}

// ---------------------------------------------------------------------------
// 5) final GEMM: 256x128 tile, 8 waves (4 row-quarters x 2 col-halves),
//    512 threads — B tile reused by 2x rows per fetch vs 128x128.
// ---------------------------------------------------------------------------
__global__ __launch_bounds__(512) void k_gemm_big(const __hip_bfloat16* __restrict__ A,
                                                  const __hip_bfloat16* __restrict__ Bt,
                                                  const float* __restrict__ bias,
                                                  float* __restrict__ C,
                                                  int N, int K) {
    __shared__ __align__(16) __hip_bfloat16 As[256 * 32];   // 16 KB
    __shared__ __align__(16) __hip_bfloat16 Bs[128 * 32];   // 8 KB
    int tid = threadIdx.x;
    int lane = tid & 63;
    int w = tid >> 6;          // 0..7
    int wr = w >> 1;           // 0..3
    int wc = w & 1;            // 0..1
    int brow = blockIdx.y * 256;
    int bcol = blockIdx.x * 128;

    f32x4 acc[4][4] = {};

    const __hip_bfloat16* gA = A  + (size_t)(brow + (tid >> 2)) * K + (tid & 3) * 8;
    const __hip_bfloat16* gB = Bt + (size_t)(bcol + (tid >> 2)) * K + (tid & 3) * 8;
    __hip_bfloat16* lA0 = As + (size_t)(w * 512);   // 512 thr cover 128 rows/round
    __hip_bfloat16* lB0 = Bs + (size_t)(w * 512);
    const size_t rstep = (size_t)128 * K;

    int r0 = wr * 64 + (lane & 15);
    int c0 = wc * 64 + (lane & 15);
    int kb = lane >> 4;

    for (int k0 = 0; k0 < K; k0 += 32) {
        gload_lds16(gA + k0,         lA0);
        gload_lds16(gA + k0 + rstep, lA0 + 4096);
        gload_lds16(gB + k0,         lB0);
        __syncthreads();

        bf16x8 af[4], bfr[4];
        #pragma unroll
        for (int m = 0; m < 4; ++m)
            af[m] = ((const bf16x8*)As)[(r0 + m * 16) * 4 + kb];
        #pragma unroll
        for (int n = 0; n < 4; ++n)
            bfr[n] = ((const bf16x8*)Bs)[(c0 + n * 16) * 4 + kb];
        #pragma unroll
        for (int m = 0; m < 4; ++m)
            #pragma unroll
            for (int n = 0; n < 4; ++n)
                acc[m][n] = __builtin_amdgcn_mfma_f32_16x16x32_bf16(af[m], bfr[n], acc[m][n], 0, 0, 0);
        __syncthreads();
    }

    int ccol = bcol + wc * 64 + (lane & 15);
    int crow = brow + wr * 64 + ((lane >> 4) << 2);
    #pragma unroll
    for (int n = 0; n < 4; ++n) {
        float bv = bias[ccol + n * 16];
        #pragma unroll
        for (int m = 0; m < 4; ++m) {
            #pragma unroll
            for (int q2 = 0; q2 < 4; ++q2) {
                float v = acc[m][n][q2] + bv;
                C[(size_t)(crow + m * 16 + q2) * N + ccol + n * 16] = v;
            }
        }
    }
}

// ---------------------------------------------------------------------------
// 6) in-place row LayerNorm
// ---------------------------------------------------------------------------
__global__ __launch_bounds__(256) void k_layernorm(float* __restrict__ X,
                                                   const float* __restrict__ g,
                                                   const float* __restrict__ bta) {
    __shared__ float rs[4], rss[4];
    int r = blockIdx.x;
    int tid = threadIdx.x;
    float* row = X + (size_t)r * HH;
    float4 v = ((float4*)row)[tid];
    float s = v.x + v.y + v.z + v.w;
    float ss = v.x * v.x + v.y * v.y + v.z * v.z + v.w * v.w;
    #pragma unroll
    for (int o = 32; o >= 1; o >>= 1) {
        s += __shfl_down(s, o);
        ss += __shfl_down(ss, o);
    }
    int w = tid >> 6;
    if ((tid & 63) == 0) { rs[w] = s; rss[w] = ss; }
    __syncthreads();
    float S = rs[0] + rs[1] + rs[2] + rs[3];
    float SS = rss[0] + rss[1] + rss[2] + rss[3];
    float mu = S * (1.f / HH);
    float var = SS * (1.f / HH) - mu * mu;
    float inv = rsqrtf(var + 1e-5f);
    float4 gg = ((const float4*)g)[tid];
    float4 bb = ((const float4*)bta)[tid];
    float4 o;
    o.x = (v.x - mu) * inv * gg.x + bb.x;
    o.y = (v.y - mu) * inv * gg.y + bb.y;
    o.z = (v.z - mu) * inv * gg.z + bb.z;
    o.w = (v.w - mu) * inv * gg.w + bb.w;
    ((float4*)row)[tid] = o;
}

// ---------------------------------------------------------------------------
extern "C" void kernel_launch(void* const* d_in, const int* in_sizes, int n_in,
                              void* d_out, int out_size, void* d_ws, size_t ws_size,
                              hipStream_t stream) {
    const int*   x    = (const int*)d_in[0];
    const float* emb  = (const float*)d_in[1];
    const float* pos  = (const float*)d_in[2];
    const float* Wq1  = (const float*)d_in[3];
    const float* Wk1  = (const float*)d_in[4];
    const float* Wq2  = (const float*)d_in[5];
    const float* Wk2  = (const float*)d_in[6];
    const float* Wq3  = (const float*)d_in[7];
    const float* Wk3  = (const float*)d_in[8];
    const float* W2   = (const float*)d_in[9];
    const float* b2   = (const float*)d_in[10];
    const float* W3   = (const float*)d_in[11];
    const float* b3   = (const float*)d_in[12];
    const float* W4   = (const float*)d_in[13];
    const float* b4   = (const float*)d_in[14];
    const float* Wout = (const float*)d_in[15];
    const float* bout = (const float*)d_in[16];
    const float* ln2g = (const float*)d_in[17];
    const float* ln2b = (const float*)d_in[18];
    const float* ln3g = (const float*)d_in[19];
    const float* ln3b = (const float*)d_in[20];

    char* wsp = (char*)d_ws;
    float* h   = (float*)wsp;                    wsp += (size_t)NROWS * HH * 4;
    float* pa  = (float*)wsp;                    wsp += (size_t)NROWS * MM * 4;
    float* pb  = (float*)wsp;                    wsp += (size_t)NROWS * MM * 4;
    __hip_bfloat16* spkb = (__hip_bfloat16*)wsp; wsp += (size_t)NROWS * HH * 2;
    __hip_bfloat16* hb   = (__hip_bfloat16*)wsp; wsp += (size_t)NROWS * HH * 2;
    __hip_bfloat16* W2t  = (__hip_bfloat16*)wsp; wsp += (size_t)HH * HH * 2;
    __hip_bfloat16* W3t  = (__hip_bfloat16*)wsp; wsp += (size_t)HH * HH * 2;
    __hip_bfloat16* W4t  = (__hip_bfloat16*)wsp; wsp += (size_t)HH * HH * 2;
    __hip_bfloat16* Wot  = (__hip_bfloat16*)wsp; wsp += (size_t)NVOCAB * HH * 2;
    float* out = (float*)d_out;

    // weight prep
    k_transpose_cvt3<<<dim3(HH / 32, HH / 32, 3), 256, 0, stream>>>(W2, W3, W4, W2t, W3t, W4t);
    k_transpose_cvt<<<dim3(NVOCAB / 32, HH / 32), 256, 0, stream>>>(Wout, Wot, HH, NVOCAB);

    dim3 gmid(HH / 128, NROWS / 128);          // (cols=8, rows=32) col-fastest
    dim3 gout(NVOCAB / 128, NROWS / 256);      // (cols=250, row-pairs=16)

    // layer 1 (embed fused into proj)
    k_proj<1><<<NROWS / 8, 256, 0, stream>>>(x, emb, pos, nullptr, Wq1, Wk1, pa, pb);
    k_scan<<<128, 64, 0, stream>>>(pa, pb, spkb);
    k_gemm_bf16<1, 0><<<gmid, 256, 0, stream>>>(spkb, W2t, b2, h, HH, HH);
    k_layernorm<<<NROWS, 256, 0, stream>>>(h, ln2g, ln2b);

    // layer 2
    k_proj<0><<<NROWS / 8, 256, 0, stream>>>(nullptr, nullptr, nullptr, h, Wq2, Wk2, pa, pb);
    k_scan<<<128, 64, 0, stream>>>(pa, pb, spkb);
    k_gemm_bf16<1, 0><<<gmid, 256, 0, stream>>>(spkb, W3t, b3, h, HH, HH);
    k_layernorm<<<NROWS, 256, 0, stream>>>(h, ln3g, ln3b);

    // layer 3 (GEMM writes bf16 directly -> hb)
    k_proj<0><<<NROWS / 8, 256, 0, stream>>>(nullptr, nullptr, nullptr, h, Wq3, Wk3, pa, pb);
    k_scan<<<128, 64, 0, stream>>>(pa, pb, spkb);
    k_gemm_bf16<1, 1><<<gmid, 256, 0, stream>>>(spkb, W4t, b4, hb, HH, HH);

    // output projection
    k_gemm_big<<<gout, 512, 0, stream>>>(hb, Wot, bout, out, NVOCAB, HH);
}

// Round 6
// 667.373 us; speedup vs baseline: 1.6568x; 1.1077x over previous
//
#include <hip/hip_runtime.h>
#include <hip/hip_bf16.h>
#include <cstddef>

#define TT 512
#define BB 8
#define HH 1024
#define MM 32
#define NVOCAB 32000
#define NROWS (TT * BB)   // 4096

typedef __attribute__((ext_vector_type(8))) short bf16x8;
typedef __attribute__((ext_vector_type(8))) unsigned short u16x8;
typedef __attribute__((ext_vector_type(4))) float f32x4;

__device__ __forceinline__ void gload_lds16(const void* g, void* l) {
    __builtin_amdgcn_global_load_lds(
        (const __attribute__((address_space(1))) void*)g,
        (__attribute__((address_space(3))) void*)l, 16, 0, 0);
}

__device__ __forceinline__ unsigned short bf16_bits(float f) {
    __hip_bfloat16 h = __float2bfloat16(f);
    return *reinterpret_cast<unsigned short*>(&h);
}

// ---------------------------------------------------------------------------
// 1) fused (embed?) + (layernorm?) + q/k proj + tau-softmax. 8 rows / block.
// ---------------------------------------------------------------------------
template <int FUSE, int DO_LN>
__global__ __launch_bounds__(256) void k_proj(const int* __restrict__ xw,
                                              const float* __restrict__ emb,
                                              const float* __restrict__ pos,
                                              const float* __restrict__ hid,
                                              const float* __restrict__ lng,
                                              const float* __restrict__ lnb,
                                              const float* __restrict__ Wq,
                                              const float* __restrict__ Wk,
                                              float* __restrict__ aout,
                                              float* __restrict__ bout_) {
    __shared__ float xs[8][HH];      // 32 KB
    __shared__ float qks[8][64];
    __shared__ float red[8][4][2];
    int r0r = blockIdx.x * 8;
    int tid = threadIdx.x;
    int lane = tid & 63;
    int w = tid >> 6;

    float4 vr[8];
    #pragma unroll
    for (int rr = 0; rr < 8; ++rr) {
        int r = r0r + rr;
        if (FUSE) {
            int idx = xw[r];
            float4 ev = ((const float4*)(emb + (size_t)idx * HH))[tid];
            float4 pv = ((const float4*)(pos + (size_t)(r >> 3) * HH))[tid];
            vr[rr] = make_float4(ev.x + pv.x, ev.y + pv.y, ev.z + pv.z, ev.w + pv.w);
        } else {
            vr[rr] = ((const float4*)(hid + (size_t)r * HH))[tid];
        }
    }

    if (DO_LN) {
        #pragma unroll
        for (int rr = 0; rr < 8; ++rr) {
            float s = vr[rr].x + vr[rr].y + vr[rr].z + vr[rr].w;
            float ss = vr[rr].x * vr[rr].x + vr[rr].y * vr[rr].y
                     + vr[rr].z * vr[rr].z + vr[rr].w * vr[rr].w;
            #pragma unroll
            for (int o = 32; o >= 1; o >>= 1) {
                s += __shfl_xor(s, o);
                ss += __shfl_xor(ss, o);
            }
            if (lane == 0) { red[rr][w][0] = s; red[rr][w][1] = ss; }
        }
        __syncthreads();
        float4 gg = ((const float4*)lng)[tid];
        float4 bb = ((const float4*)lnb)[tid];
        #pragma unroll
        for (int rr = 0; rr < 8; ++rr) {
            float S  = red[rr][0][0] + red[rr][1][0] + red[rr][2][0] + red[rr][3][0];
            float SS = red[rr][0][1] + red[rr][1][1] + red[rr][2][1] + red[rr][3][1];
            float mu = S * (1.f / HH);
            float inv = rsqrtf(SS * (1.f / HH) - mu * mu + 1e-5f);
            vr[rr].x = (vr[rr].x - mu) * inv * gg.x + bb.x;
            vr[rr].y = (vr[rr].y - mu) * inv * gg.y + bb.y;
            vr[rr].z = (vr[rr].z - mu) * inv * gg.z + bb.z;
            vr[rr].w = (vr[rr].w - mu) * inv * gg.w + bb.w;
        }
    }

    #pragma unroll
    for (int rr = 0; rr < 8; ++rr)
        ((float4*)xs[rr])[tid] = vr[rr];
    __syncthreads();

    int col = tid >> 2;       // 0..63 (0..31 q, 32..63 k)
    int seg = tid & 3;
    const float* W = (col < 32) ? Wq : Wk;
    int c = col & 31;
    int h0 = seg * 256;
    float s[8] = {0.f, 0.f, 0.f, 0.f, 0.f, 0.f, 0.f, 0.f};
    for (int hh = 0; hh < 256; ++hh) {
        float wv = W[(size_t)(h0 + hh) * MM + c];
        #pragma unroll
        for (int rr = 0; rr < 8; ++rr)
            s[rr] = fmaf(xs[rr][h0 + hh], wv, s[rr]);
    }
    #pragma unroll
    for (int rr = 0; rr < 8; ++rr) {
        float t = s[rr];
        t += __shfl_down(t, 1);
        t += __shfl_down(t, 2);
        if (seg == 0) qks[rr][col] = t;
    }
    __syncthreads();

    #pragma unroll
    for (int g = 0; g < 2; ++g) {
        int rr = g * 4 + (tid >> 6);
        int l2 = tid & 63;
        float v = qks[rr][l2] * 0.5f;      // / tau
        float m = v;
        #pragma unroll
        for (int o = 16; o >= 1; o >>= 1) m = fmaxf(m, __shfl_xor(m, o));
        float e = expf(v - m);
        float ss2 = e;
        #pragma unroll
        for (int o = 16; o >= 1; o >>= 1) ss2 += __shfl_xor(ss2, o);
        float res = e / ss2;
        size_t r = r0r + rr;
        if (l2 < 32) aout[r * MM + l2] = res;
        else         bout_[r * MM + (l2 - 32)] = res;
    }
}

// ---------------------------------------------------------------------------
// 2) leaky associative scan -> bf16 spikes. 128 blocks (8 b x 16 ig), 64 thr.
// ---------------------------------------------------------------------------
#define CHUNK 128
__global__ __launch_bounds__(64) void k_scan(const float* __restrict__ a,
                                             const float* __restrict__ bsm,
                                             __hip_bfloat16* __restrict__ spk) {
    __shared__ float sa[CHUNK * 2];
    __shared__ float sb[CHUNK * MM];
    int bb = blockIdx.x >> 4;
    int ig = blockIdx.x & 15;
    int tid = threadIdx.x;
    int i2 = tid >> 5, j = tid & 31;
    int i = ig * 2 + i2;
    float mem = 0.f;
    for (int t0 = 0; t0 < TT; t0 += CHUNK) {
        __syncthreads();
        for (int v = tid; v < CHUNK * 8; v += 64) {
            int tt = v >> 3, p = v & 7;
            ((float4*)sb)[v] = ((const float4*)bsm)[((size_t)(t0 + tt) * BB + bb) * 8 + p];
        }
        for (int v = tid; v < CHUNK * 2; v += 64) {
            int tt = v >> 1, ii = v & 1;
            sa[v] = a[((size_t)(t0 + tt) * BB + bb) * MM + ig * 2 + ii];
        }
        __syncthreads();
        for (int tt = 0; tt < CHUNK; ++tt) {
            float av = sa[tt * 2 + i2];
            float bv = sb[tt * MM + j];
            mem = fmaf(0.9f, mem, av * bv);
            float sv = (mem > 1.0f) ? 1.0f : 0.0f;
            spk[((size_t)(t0 + tt) * BB + bb) * HH + i * MM + j] = __float2bfloat16(sv);
            mem -= sv;
        }
    }
}

// ---------------------------------------------------------------------------
// 3a) 3 mid weights [1024][1024] fp32 -> bf16 transposed (fused)
// ---------------------------------------------------------------------------
__global__ __launch_bounds__(256) void k_transpose_cvt3(const float* __restrict__ Wa,
                                                        const float* __restrict__ Wb,
                                                        const float* __restrict__ Wc,
                                                        __hip_bfloat16* __restrict__ Ta,
                                                        __hip_bfloat16* __restrict__ Tb,
                                                        __hip_bfloat16* __restrict__ Tc) {
    const float* W = (blockIdx.z == 0) ? Wa : (blockIdx.z == 1) ? Wb : Wc;
    __hip_bfloat16* Wt = (blockIdx.z == 0) ? Ta : (blockIdx.z == 1) ? Tb : Tc;
    __shared__ float t[32][33];
    int n0 = blockIdx.x * 32;
    int k0 = blockIdx.y * 32;
    int tx = threadIdx.x & 31, ty = threadIdx.x >> 5;
    #pragma unroll
    for (int r = 0; r < 4; ++r)
        t[ty + r * 8][tx] = W[(size_t)(k0 + ty + r * 8) * HH + n0 + tx];
    __syncthreads();
    #pragma unroll
    for (int r = 0; r < 4; ++r)
        Wt[(size_t)(n0 + ty + r * 8) * HH + k0 + tx] = __float2bfloat16(t[tx][ty + r * 8]);
}

// ---------------------------------------------------------------------------
// 3b) Wout [K][N] fp32 -> [N][K] bf16, vectorized (float4 in, 16B out)
// ---------------------------------------------------------------------------
__global__ __launch_bounds__(256) void k_transpose_cvt_v4(const float* __restrict__ W,
                                                          __hip_bfloat16* __restrict__ Wt,
                                                          int K, int N) {
    __shared__ float t[32][68];
    int n0 = blockIdx.x * 64;
    int k0 = blockIdx.y * 32;
    int tid = threadIdx.x;
    #pragma unroll
    for (int it = 0; it < 2; ++it) {
        int idx = tid + it * 256;         // 0..511
        int kk = idx >> 4;                // 0..31
        int nn = (idx & 15) * 4;          // 0..60
        *(float4*)&t[kk][nn] = *(const float4*)(W + (size_t)(k0 + kk) * N + n0 + nn);
    }
    __syncthreads();
    int nn = tid >> 2;                    // 0..63
    int kc = (tid & 3) * 8;               // 0,8,16,24
    u16x8 o;
    #pragma unroll
    for (int u = 0; u < 8; ++u) o[u] = bf16_bits(t[kc + u][nn]);
    *(u16x8*)(Wt + (size_t)(n0 + nn) * K + k0 + kc) = o;
}

// ---------------------------------------------------------------------------
// 4) mid bf16 MFMA GEMM: m97 128x128, 4 waves, BK=32 (unchanged, passing)
// ---------------------------------------------------------------------------
template <int DO_RELU, int BF16_OUT>
__global__ __launch_bounds__(256) void k_gemm_bf16(const __hip_bfloat16* __restrict__ A,
                                                   const __hip_bfloat16* __restrict__ Bt,
                                                   const float* __restrict__ bias,
                                                   void* __restrict__ Cv,
                                                   int N, int K) {
    __shared__ __align__(16) __hip_bfloat16 As[128 * 32];
    __shared__ __align__(16) __hip_bfloat16 Bs[128 * 32];
    int tid = threadIdx.x;
    int lane = tid & 63;
    int w = tid >> 6;
    int wr = w >> 1, wc = w & 1;
    int brow = blockIdx.y * 128;
    int bcol = blockIdx.x * 128;

    f32x4 acc[4][4] = {};

    const __hip_bfloat16* gA = A  + (size_t)(brow + (tid >> 2)) * K + (tid & 3) * 8;
    const __hip_bfloat16* gB = Bt + (size_t)(bcol + (tid >> 2)) * K + (tid & 3) * 8;
    __hip_bfloat16* lA0 = As + (size_t)(w * 512);
    __hip_bfloat16* lB0 = Bs + (size_t)(w * 512);
    const size_t rstep = (size_t)64 * K;

    int r0 = wr * 64 + (lane & 15);
    int c0 = wc * 64 + (lane & 15);
    int kb = lane >> 4;

    for (int k0 = 0; k0 < K; k0 += 32) {
        gload_lds16(gA + k0,         lA0);
        gload_lds16(gA + k0 + rstep, lA0 + 2048);
        gload_lds16(gB + k0,         lB0);
        gload_lds16(gB + k0 + rstep, lB0 + 2048);
        __syncthreads();

        bf16x8 af[4], bfr[4];
        #pragma unroll
        for (int m = 0; m < 4; ++m)
            af[m] = ((const bf16x8*)As)[(r0 + m * 16) * 4 + kb];
        #pragma unroll
        for (int n = 0; n < 4; ++n)
            bfr[n] = ((const bf16x8*)Bs)[(c0 + n * 16) * 4 + kb];
        #pragma unroll
        for (int m = 0; m < 4; ++m)
            #pragma unroll
            for (int n = 0; n < 4; ++n)
                acc[m][n] = __builtin_amdgcn_mfma_f32_16x16x32_bf16(af[m], bfr[n], acc[m][n], 0, 0, 0);
        __syncthreads();
    }

    int ccol = bcol + wc * 64 + (lane & 15);
    int crow = brow + wr * 64 + ((lane >> 4) << 2);
    #pragma unroll
    for (int n = 0; n < 4; ++n) {
        float bv = bias[ccol + n * 16];
        #pragma unroll
        for (int m = 0; m < 4; ++m) {
            #pragma unroll
            for (int q2 = 0; q2 < 4; ++q2) {
                float v = acc[m][n][q2] + bv;
                if (DO_RELU) v = fmaxf(v, 0.f);
                size_t off = (size_t)(crow + m * 16 + q2) * N + ccol + n * 16;
                if (BF16_OUT) ((__hip_bfloat16*)Cv)[off] = __float2bfloat16(v);
                else          ((float*)Cv)[off] = v;
            }
        }
    }
}

// ---------------------------------------------------------------------------
// 5) final GEMM: 256x128 tile, 8 waves, BK=32, TRIPLE-buffered LDS with
//    counted vmcnt (loads stay in flight across barriers; one barrier/K-step).
//    Safety: vmcnt(3) retires tile t (per-thread 3 loads, in-order);
//    buffer (t+2)%3 is only rewritten after the barrier proving all waves
//    consumed tile t-1 (their ds_reads lgkm-drained before MFMA issue).
// ---------------------------------------------------------------------------
__global__ __launch_bounds__(512) void k_gemm_big(const __hip_bfloat16* __restrict__ A,
                                                  const __hip_bfloat16* __restrict__ Bt,
                                                  const float* __restrict__ bias,
                                                  float* __restrict__ C,
                                                  int N, int K) {
    __shared__ __align__(16) __hip_bfloat16 As[3 * 256 * 32];   // 48 KB
    __shared__ __align__(16) __hip_bfloat16 Bs[3 * 128 * 32];   // 24 KB
    int tid = threadIdx.x;
    int lane = tid & 63;
    int w = tid >> 6;          // 0..7
    int wr = w >> 1;           // 0..3
    int wc = w & 1;            // 0..1
    int brow = blockIdx.y * 256;
    int bcol = blockIdx.x * 128;

    f32x4 acc[4][4] = {};

    const __hip_bfloat16* gA = A  + (size_t)(brow + (tid >> 2)) * K + (tid & 3) * 8;
    const __hip_bfloat16* gB = Bt + (size_t)(bcol + (tid >> 2)) * K + (tid & 3) * 8;
    const size_t rstep = (size_t)128 * K;
    __hip_bfloat16* lA = As + (size_t)(w * 512);
    __hip_bfloat16* lB = Bs + (size_t)(w * 512);

    int r0 = wr * 64 + (lane & 15);
    int c0 = wc * 64 + (lane & 15);
    int kb = lane >> 4;
    const int NT = K / 32;     // 32 K-tiles

#define STAGE_BIG(t, q) do {                                    \
        gload_lds16(gA + (size_t)(t) * 32,         lA + (q) * 8192);        \
        gload_lds16(gA + (size_t)(t) * 32 + rstep, lA + (q) * 8192 + 4096); \
        gload_lds16(gB + (size_t)(t) * 32,         lB + (q) * 4096);        \
    } while (0)

    STAGE_BIG(0, 0);
    STAGE_BIG(1, 1);

    int q = 0, qs = 2;
    for (int t = 0; t < NT; ++t) {
        if (t < NT - 1) asm volatile("s_waitcnt vmcnt(3)" ::: "memory");
        else            asm volatile("s_waitcnt vmcnt(0)" ::: "memory");
        __builtin_amdgcn_s_barrier();
        if (t + 2 < NT) {
            STAGE_BIG(t + 2, qs);
            qs = (qs == 2) ? 0 : qs + 1;
        }

        const bf16x8* Ab = (const bf16x8*)(As + q * 8192);
        const bf16x8* Bb = (const bf16x8*)(Bs + q * 4096);
        q = (q == 2) ? 0 : q + 1;

        bf16x8 af[4], bfr[4];
        #pragma unroll
        for (int m = 0; m < 4; ++m) af[m] = Ab[(r0 + m * 16) * 4 + kb];
        #pragma unroll
        for (int n = 0; n < 4; ++n) bfr[n] = Bb[(c0 + n * 16) * 4 + kb];

        __builtin_amdgcn_s_setprio(1);
        #pragma unroll
        for (int m = 0; m < 4; ++m)
            #pragma unroll
            for (int n = 0; n < 4; ++n)
                acc[m][n] = __builtin_amdgcn_mfma_f32_16x16x32_bf16(af[m], bfr[n], acc[m][n], 0, 0, 0);
        __builtin_amdgcn_s_setprio(0);
    }
#undef STAGE_BIG

    int ccol = bcol + wc * 64 + (lane & 15);
    int crow = brow + wr * 64 + ((lane >> 4) << 2);
    #pragma unroll
    for (int n = 0; n < 4; ++n) {
        float bv = bias[ccol + n * 16];
        #pragma unroll
        for (int m = 0; m < 4; ++m) {
            #pragma unroll
            for (int q2 = 0; q2 < 4; ++q2) {
                float v = acc[m][n][q2] + bv;
                __builtin_nontemporal_store(v, C + (size_t)(crow + m * 16 + q2) * N + ccol + n * 16);
            }
        }
    }
}

// ---------------------------------------------------------------------------
extern "C" void kernel_launch(void* const* d_in, const int* in_sizes, int n_in,
                              void* d_out, int out_size, void* d_ws, size_t ws_size,
                              hipStream_t stream) {
    const int*   x    = (const int*)d_in[0];
    const float* emb  = (const float*)d_in[1];
    const float* pos  = (const float*)d_in[2];
    const float* Wq1  = (const float*)d_in[3];
    const float* Wk1  = (const float*)d_in[4];
    const float* Wq2  = (const float*)d_in[5];
    const float* Wk2  = (const float*)d_in[6];
    const float* Wq3  = (const float*)d_in[7];
    const float* Wk3  = (const float*)d_in[8];
    const float* W2   = (const float*)d_in[9];
    const float* b2   = (const float*)d_in[10];
    const float* W3   = (const float*)d_in[11];
    const float* b3   = (const float*)d_in[12];
    const float* W4   = (const float*)d_in[13];
    const float* b4   = (const float*)d_in[14];
    const float* Wout = (const float*)d_in[15];
    const float* bout = (const float*)d_in[16];
    const float* ln2g = (const float*)d_in[17];
    const float* ln2b = (const float*)d_in[18];
    const float* ln3g = (const float*)d_in[19];
    const float* ln3b = (const float*)d_in[20];

    char* wsp = (char*)d_ws;
    float* h   = (float*)wsp;                    wsp += (size_t)NROWS * HH * 4;
    float* pa  = (float*)wsp;                    wsp += (size_t)NROWS * MM * 4;
    float* pb  = (float*)wsp;                    wsp += (size_t)NROWS * MM * 4;
    __hip_bfloat16* spkb = (__hip_bfloat16*)wsp; wsp += (size_t)NROWS * HH * 2;
    __hip_bfloat16* hb   = (__hip_bfloat16*)wsp; wsp += (size_t)NROWS * HH * 2;
    __hip_bfloat16* W2t  = (__hip_bfloat16*)wsp; wsp += (size_t)HH * HH * 2;
    __hip_bfloat16* W3t  = (__hip_bfloat16*)wsp; wsp += (size_t)HH * HH * 2;
    __hip_bfloat16* W4t  = (__hip_bfloat16*)wsp; wsp += (size_t)HH * HH * 2;
    __hip_bfloat16* Wot  = (__hip_bfloat16*)wsp; wsp += (size_t)NVOCAB * HH * 2;
    float* out = (float*)d_out;

    // weight prep
    k_transpose_cvt3<<<dim3(HH / 32, HH / 32, 3), 256, 0, stream>>>(W2, W3, W4, W2t, W3t, W4t);
    k_transpose_cvt_v4<<<dim3(NVOCAB / 64, HH / 32), 256, 0, stream>>>(Wout, Wot, HH, NVOCAB);

    dim3 gmid(HH / 128, NROWS / 128);          // (cols=8, rows=32) col-fastest
    dim3 gout(NVOCAB / 128, NROWS / 256);      // (cols=250, row-pairs=16)

    // layer 1 (embed fused into proj)
    k_proj<1, 0><<<NROWS / 8, 256, 0, stream>>>(x, emb, pos, nullptr, nullptr, nullptr, Wq1, Wk1, pa, pb);
    k_scan<<<128, 64, 0, stream>>>(pa, pb, spkb);
    k_gemm_bf16<1, 0><<<gmid, 256, 0, stream>>>(spkb, W2t, b2, h, HH, HH);

    // layer 2 (LN fused into proj)
    k_proj<0, 1><<<NROWS / 8, 256, 0, stream>>>(nullptr, nullptr, nullptr, h, ln2g, ln2b, Wq2, Wk2, pa, pb);
    k_scan<<<128, 64, 0, stream>>>(pa, pb, spkb);
    k_gemm_bf16<1, 0><<<gmid, 256, 0, stream>>>(spkb, W3t, b3, h, HH, HH);

    // layer 3 (LN fused into proj; GEMM writes bf16 -> hb)
    k_proj<0, 1><<<NROWS / 8, 256, 0, stream>>>(nullptr, nullptr, nullptr, h, ln3g, ln3b, Wq3, Wk3, pa, pb);
    k_scan<<<128, 64, 0, stream>>>(pa, pb, spkb);
    k_gemm_bf16<1, 1><<<gmid, 256, 0, stream>>>(spkb, W4t, b4, hb, HH, HH);

    // output projection (pipelined, counted vmcnt)
    k_gemm_big<<<gout, 512, 0, stream>>>(hb, Wot, bout, out, NVOCAB, HH);
}